// Round 2
// baseline (1106.507 us; speedup 1.0000x reference)
//
#include <hip/hip_runtime.h>
#include <cstdint>
#include <cstddef>

#define N_PRIORS 65536
#define N_BATCH  32
#define N_COLS   84
#define TOPK     400
#define KEEPK    200
#define CAND_CAP 2048
#define NBINS    8192   // top 13 bits of monotonic key

__device__ __forceinline__ uint32_t f2mono(float f) {
    uint32_t u = __float_as_uint(f);
    return u ^ ((u & 0x80000000u) ? 0xFFFFFFFFu : 0x80000000u);
}
__device__ __forceinline__ float mono2f(uint32_t m) {
    uint32_t u = (m & 0x80000000u) ? (m ^ 0x80000000u) : ~m;
    return __uint_as_float(u);
}

// ------------- Kernel 1: per-prior masked max over 80 class confs (mono u32) -------
__global__ __launch_bounds__(256) void k1_score(
    const float* __restrict__ pred, uint32_t* __restrict__ scores) {
    int tid = blockIdx.x * 256 + threadIdx.x;           // [0, 32*65536)
    const float4* base = (const float4*)(pred + (size_t)tid * N_COLS);
    float best = -3.4e38f;
#pragma unroll
    for (int c = 0; c < 20; ++c) {
        float4 v = base[c + 1];                         // conf elems 4+4c .. 7+4c
        best = fmaxf(best, fmaxf(fmaxf(v.x, v.y), fmaxf(v.z, v.w)));
    }
    float m = (best > 0.5f) ? best : -INFINITY;         // CONF_THR mask
    scores[tid] = f2mono(m);
}

// ---------------- Kernel 2: exact top-400 per batch (histogram select + bitonic) ----
__global__ __launch_bounds__(1024) void k2_topk(
    const uint32_t* __restrict__ scores, unsigned long long* __restrict__ topk) {
    __shared__ uint32_t hist[NBINS];                    // 32 KB
    __shared__ unsigned long long cand[CAND_CAP];       // 16 KB
    __shared__ uint32_t sfx[1024];                      // 4 KB
    __shared__ int shB;
    __shared__ int shCnt;

    const int b = blockIdx.x, t = threadIdx.x;
    const uint32_t* sc = scores + (size_t)b * N_PRIORS;

    for (int i = t; i < NBINS; i += 1024) hist[i] = 0;
    if (t == 0) shCnt = 0;
    __syncthreads();

    // Phase A: histogram of masked-score prefixes
    for (int k = 0; k < N_PRIORS / 1024; ++k)
        atomicAdd(&hist[sc[k * 1024 + t] >> 19], 1u);
    __syncthreads();

    // Phase B: suffix-sum over 8-bin chunks, locate threshold bin B
    uint32_t part = 0;
#pragma unroll
    for (int i = 0; i < 8; ++i) part += hist[t * 8 + i];
    sfx[t] = part;
    __syncthreads();
    for (int stride = 1; stride < 1024; stride <<= 1) {
        uint32_t v = sfx[t];
        if (t + stride < 1024) v += sfx[t + stride];
        __syncthreads();
        sfx[t] = v;
        __syncthreads();
    }
    if (sfx[t] >= TOPK && (t == 1023 || sfx[t + 1] < TOPK)) {
        uint32_t cumAbove = (t == 1023) ? 0u : sfx[t + 1];
        int B = t * 8;
        for (int bin = t * 8 + 7; bin >= t * 8; --bin) {
            cumAbove += hist[bin];
            if (cumAbove >= TOPK) { B = bin; break; }
        }
        shB = B;
    }
    __syncthreads();
    // valid scores (>0.5) always have prefix >= 4096; -inf has prefix 15.
    // Floor at 4096 so -inf entries never enter compaction.
    uint32_t Beff = (uint32_t)max(shB, 4096);

    // Phase C: compact candidate keys (desc score, asc idx on ties)
    for (int k = 0; k < N_PRIORS / 1024; ++k) {
        int idx = k * 1024 + t;
        uint32_t mono = sc[idx];
        if ((mono >> 19) >= Beff) {
            int pos = atomicAdd(&shCnt, 1);
            if (pos < CAND_CAP)
                cand[pos] = ((unsigned long long)(~mono) << 32) | (uint32_t)idx;
        }
    }
    __syncthreads();
    int cnt = min(shCnt, CAND_CAP);
    for (int i = cnt + t; i < CAND_CAP; i += 1024) cand[i] = 0xFFFFFFFFFFFFFFFFull;
    __syncthreads();

    // Phase D: bitonic sort ascending (2048 keys, 1024 threads)
    for (int k = 2; k <= CAND_CAP; k <<= 1) {
        for (int j = k >> 1; j > 0; j >>= 1) {
#pragma unroll
            for (int e = 0; e < 2; ++e) {
                int i = t + e * 1024;
                int ixj = i ^ j;
                if (ixj > i) {
                    bool asc = ((i & k) == 0);
                    unsigned long long a = cand[i], c = cand[ixj];
                    if ((a > c) == asc) { cand[i] = c; cand[ixj] = a; }
                }
            }
            __syncthreads();
        }
    }

    // Phase E: emit top 400 (pad with -inf sentinels, matching jax zero-rows)
    if (t < TOPK) {
        unsigned long long key =
            (t < cnt) ? cand[t] : (((unsigned long long)0xFF800000u) << 32);
        topk[b * TOPK + t] = key;
    }
}

// ---------------- Kernel 3: decode + label + NMS + rank-by-ymin + emit --------------
__global__ __launch_bounds__(256) void k3_nms_out(
    const float* __restrict__ pred, const float* __restrict__ priors,
    const unsigned long long* __restrict__ topk, float* __restrict__ out) {
    __shared__ float bx0[TOPK], by0[TOPK], bx1[TOPK], by1[TOPK];
    __shared__ float barea[TOPK], bscore[TOPK], bykey[TOPK];
    __shared__ uint8_t blab[TOPK];
    __shared__ unsigned long long sup[TOPK * 8];        // 25.6 KB, row-stride 8 words
    __shared__ unsigned long long keepw[8];

    const int b = blockIdx.x, t = threadIdx.x;
    if (t < 8) keepw[t] = 0ull;
    __syncthreads();

    // decode selected boxes + recompute argmax label (first-max tie-break)
    for (int i = t; i < TOPK; i += 256) {
        unsigned long long key = topk[b * TOPK + i];
        uint32_t idx = (uint32_t)key;
        uint32_t mono = ~(uint32_t)(key >> 32);
        float score = mono2f(mono);
        bool valid = score > 0.5f;
        const float4* row = (const float4*)(pred + ((size_t)b * N_PRIORS + idx) * N_COLS);
        const float4 loc = row[0];
        const float4 pr  = *(const float4*)(priors + (size_t)idx * 4);
        float cx = pr.x + loc.x * 0.1f * pr.z;
        float cy = pr.y + loc.y * 0.1f * pr.w;
        float w  = pr.z * expf(loc.z * 0.2f);
        float h  = pr.w * expf(loc.w * 0.2f);
        float x0 = cx - w * 0.5f, y0 = cy - h * 0.5f;
        float x1 = cx + w * 0.5f, y1 = cy + h * 0.5f;
        bx0[i] = x0; by0[i] = y0; bx1[i] = x1; by1[i] = y1;
        barea[i] = (x1 - x0) * (y1 - y0);
        bscore[i] = score;
        float best = -3.4e38f;
        int lab = 0;
#pragma unroll
        for (int c = 0; c < 20; ++c) {
            float4 v = row[c + 1];
            int j = c * 4;
            if (v.x > best) { best = v.x; lab = j; }
            if (v.y > best) { best = v.y; lab = j + 1; }
            if (v.z > best) { best = v.z; lab = j + 2; }
            if (v.w > best) { best = v.w; lab = j + 3; }
        }
        blab[i] = (uint8_t)lab;
        if (valid) atomicOr(&keepw[i >> 6], 1ull << (i & 63));
    }
    __syncthreads();

    // suppression bitmask: sup[i] bit j = (IoU(i,j) > 0.5) && (j > i)
    for (int task = t; task < TOPK * 7; task += 256) {
        int i = task / 7, w = task % 7;
        int jbase = w * 64;
        unsigned long long bits = 0;
        if (jbase + 63 > i) {
            float ax0 = bx0[i], ay0 = by0[i], ax1 = bx1[i], ay1 = by1[i], aa = barea[i];
            int jend = min(jbase + 64, TOPK);
            for (int j = max(jbase, i + 1); j < jend; ++j) {
                float lx = fmaxf(ax0, bx0[j]);
                float ly = fmaxf(ay0, by0[j]);
                float rx = fminf(ax1, bx1[j]);
                float ry = fminf(ay1, by1[j]);
                float iw = fmaxf(rx - lx, 0.0f);
                float ih = fmaxf(ry - ly, 0.0f);
                float inter = iw * ih;
                float iou = inter / (aa + barea[j] - inter + 1e-9f);
                if (iou > 0.5f) bits |= 1ull << (j & 63);
            }
        }
        sup[i * 8 + w] = bits;
    }
    __syncthreads();

    // greedy serial keep recurrence on one wave (lanes 0..6 own the 7 keep words)
    if (t < 64) {
        unsigned long long kw = (t < 7) ? keepw[t] : 0ull;
        for (int i = 0; i < TOPK; ++i) {
            unsigned long long wv = __shfl(kw, i >> 6, 64);
            unsigned long long bit = (wv >> (i & 63)) & 1ull;
            unsigned long long msk = 0ull - bit;        // all-ones iff keep[i]
            if (t < 7) kw &= ~(sup[i * 8 + t] & msk);
        }
        if (t < 7) keepw[t] = kw;
    }
    __syncthreads();

    // sort key: kept ? ymin : +inf
    for (int i = t; i < TOPK; i += 256) {
        bool keep = (keepw[i >> 6] >> (i & 63)) & 1ull;
        bykey[i] = keep ? by0[i] : INFINITY;
    }
    __syncthreads();

    // stable pairwise rank; emit rows 0..199 (every row written exactly once)
    for (int i = t; i < TOPK; i += 256) {
        float ki = bykey[i];
        int rank = 0;
        for (int j = 0; j < TOPK; ++j) {
            float kj = bykey[j];
            rank += (kj < ki) || (kj == ki && j < i);
        }
        if (rank < KEEPK) {
            bool keep = (keepw[i >> 6] >> (i & 63)) & 1ull;
            float* o = out + ((size_t)b * KEEPK + rank) * 6;
            if (keep) {
                o[0] = bx0[i]; o[1] = by0[i]; o[2] = bx1[i]; o[3] = by1[i];
                o[4] = (float)blab[i]; o[5] = bscore[i];
            } else {
                o[0] = 0.0f; o[1] = 0.0f; o[2] = 0.0f;
                o[3] = 0.0f; o[4] = 0.0f; o[5] = 0.0f;
            }
        }
    }
}

extern "C" void kernel_launch(void* const* d_in, const int* in_sizes, int n_in,
                              void* d_out, int out_size, void* d_ws, size_t ws_size,
                              hipStream_t stream) {
    const float* pred   = (const float*)d_in[0];   // (32, 65536, 84) f32
    const float* priors = (const float*)d_in[1];   // (65536, 4) f32
    float* out = (float*)d_out;                    // (32, 200, 6) f32

    char* ws = (char*)d_ws;
    uint32_t* scores = (uint32_t*)ws;                              // 8 MB
    unsigned long long* topk =
        (unsigned long long*)(ws + (size_t)8 * 1024 * 1024);       // 100 KB

    k1_score<<<(N_BATCH * N_PRIORS) / 256, 256, 0, stream>>>(pred, scores);
    k2_topk<<<N_BATCH, 1024, 0, stream>>>(scores, topk);
    k3_nms_out<<<N_BATCH, 256, 0, stream>>>(pred, priors, topk, out);
}